// Round 4
// baseline (93.729 us; speedup 1.0000x reference)
//
#include <hip/hip_runtime.h>

#define NS   128          // samples
#define D_   8128         // feature dim
#define P_   8128         // pairs
#define EPSV 1e-12f
#define NT   127          // 8128 / 64 tiles
#define CH   127          // column chunks of 64

// ---- bf16 helpers (OCP bf16 = top 16 bits of f32, RNE) ----
static __device__ __forceinline__ unsigned short f32_to_bf16_rne(float f) {
    unsigned int u = __float_as_uint(f);
    return (unsigned short)((u + 0x7fffu + ((u >> 16) & 1u)) >> 16);
}
static __device__ __forceinline__ float bf16_lo(unsigned int u) {   // element 2k
    return __uint_as_float(u << 16);
}
static __device__ __forceinline__ float bf16_hi(unsigned int u) {   // element 2k+1
    return __uint_as_float(u & 0xffff0000u);
}

// Rt LDS addressing: stride 68 (16B-aligned rows), q-octet XOR swizzle so the
// scalar staging writes and b128 compute reads are both ~2-way (free).
__device__ __forceinline__ int RTIDX(int p, int q) {
    return p * 68 + 8 * (((q) >> 3) ^ ((p >> 3) & 7)) + (q & 7);
}

// ============ kernel A: fp32 -> bf16 copies of both matrices ============
__global__ void cvt_bf16(const float* __restrict__ Sr, const float* __restrict__ Sf,
                         unsigned short* __restrict__ Sr16, unsigned short* __restrict__ Sf16) {
    int tid = blockIdx.x * 256 + threadIdx.x;        // 0 .. 2*260096-1
    const int half = NS * D_ / 4;                    // 260096 float4s per matrix
    const float* src = (tid < half) ? Sr : Sf;
    unsigned short* dst = (tid < half) ? Sr16 : Sf16;
    int e = (tid < half) ? tid : tid - half;
    float4 v = *(const float4*)(src + 4 * (size_t)e);
    ushort4 o;
    o.x = f32_to_bf16_rne(v.x);
    o.y = f32_to_bf16_rne(v.y);
    o.z = f32_to_bf16_rne(v.z);
    o.w = f32_to_bf16_rne(v.w);
    *(ushort4*)(dst + 4 * (size_t)e) = o;
}

// ============ kernel B: partial pair-norms per 64-column chunk ============
// grid (127, 2), 512 threads. Stage S[:,chunk] in LDS (float4-slot XOR swizzle),
// thread owns 16 consecutive pairs: row-i cached in regs, row-j read from LDS.
__global__ void __launch_bounds__(512, 2)
norm_partial(const float* __restrict__ Sr, const float* __restrict__ Sf,
             float* __restrict__ npart) {
    int c = blockIdx.x;       // column chunk
    int m = blockIdx.y;       // 0 = real, 1 = fake
    const float* __restrict__ S = m ? Sf : Sr;
    __shared__ float4 lds4[128][16];
    int t = threadIdx.x;

    #pragma unroll
    for (int s = 0; s < 4; ++s) {
        int e4 = t + 512 * s;            // 0..2047
        int r  = e4 >> 4;                // row 0..127
        int g  = e4 & 15;                // float4 index
        lds4[r][g ^ ((r >> 4) & 15)] =
            *(const float4*)(S + (size_t)r * D_ + c * 64 + 4 * g);
    }
    __syncthreads();

    int p0 = 16 * t;
    if (p0 < P_) {
        // invert p0 -> (i, j) for tril_indices(N,-1) order
        int i = (int)((1.0f + sqrtf(8.0f * (float)p0 + 1.0f)) * 0.5f);
        while (i * (i - 1) / 2 > p0) --i;
        while ((i + 1) * i / 2 <= p0) ++i;
        int j = p0 - i * (i - 1) / 2;

        float4 ric[16];
        int cur_i = -1;
        float* dst = npart + ((size_t)m * CH + c) * P_;

        for (int k = 0; k < 16; ++k) {
            int p = p0 + k;
            if (p >= P_) break;
            if (j >= i) { j = 0; ++i; }          // advance to next triangle row
            if (i != cur_i) {
                int sw = (i >> 4) & 15;
                #pragma unroll
                for (int g = 0; g < 16; ++g) ric[g] = lds4[i][g ^ sw];
                cur_i = i;
            }
            int swj = (j >> 4) & 15;
            float acc = 0.f;
            #pragma unroll
            for (int g = 0; g < 16; ++g) {
                float4 b = lds4[j][g ^ swj];
                float4 a = ric[g];
                float dx = a.x - b.x, dy = a.y - b.y, dz = a.z - b.z, dw = a.w - b.w;
                acc += dx * dx + dy * dy + dz * dz + dw * dw;
            }
            dst[p] = acc;
            ++j;
        }
    }
}

// ============ kernel C: reduce partials + pair metadata ============
__global__ void norm_finish(const float* __restrict__ npart,
                            float* __restrict__ inv_nr, float* __restrict__ inv_nf,
                            int* __restrict__ opi, int* __restrict__ opj) {
    int p = blockIdx.x * 256 + threadIdx.x;
    if (p >= P_) return;
    const float* br = npart + p;
    const float* bf = npart + (size_t)CH * P_ + p;
    float sr = 0.f, sf = 0.f;
    for (int cc = 0; cc < CH; ++cc) {
        sr += br[(size_t)cc * P_];
        sf += bf[(size_t)cc * P_];
    }
    int i = (int)((1.0f + sqrtf(8.0f * (float)p + 1.0f)) * 0.5f);
    while (i * (i - 1) / 2 > p) --i;
    while ((i + 1) * i / 2 <= p) ++i;
    int j = p - i * (i - 1) / 2;
    inv_nr[p] = rsqrtf(sr);
    inv_nf[p] = rsqrtf(sf);
    opi[p] = i * D_;
    opj[p] = j * D_;
}

// ============ kernel D: bf16 tile product ============
// grid (NT, NT), 256 threads. Rt (fp32, swizzled) staged from bf16 Sr;
// F recomputed inline from bf16 Sf with ushort8 (b128) loads.
__global__ void __launch_bounds__(256, 6)
tile4_kernel(const unsigned short* __restrict__ Sr16, const unsigned short* __restrict__ Sf16,
             const float* __restrict__ inv_nr, const float* __restrict__ inv_nf,
             const int* __restrict__ opi, const int* __restrict__ opj,
             float* __restrict__ partials) {
    __shared__ float Rt[64 * 68];
    __shared__ int   sIp[64], sJp[64];
    __shared__ float sInvF[64];
    __shared__ float wsum[4];

    int t  = threadIdx.x;
    int p0 = blockIdx.x * 64, q0 = blockIdx.y * 64;

    if (t < 64) {
        int p = p0 + t;
        sIp[t]   = opi[p];
        sJp[t]   = opj[p];
        sInvF[t] = inv_nf[p];
    }

    // ---- stage Rt[p][q] = max((Sr[i_q][p]-Sr[j_q][p])*inv_nr[q], eps)
    // 512 tasks = 64 q-rows x 8 col-groups of 8 p's
    #pragma unroll
    for (int pass = 0; pass < 2; ++pass) {
        int task = t + 256 * pass;
        int qq = task >> 3, cg = task & 7;
        int q  = q0 + qq;
        int oiq = opi[q], ojq = opj[q];
        float invr = inv_nr[q];
        uint4 ua = *(const uint4*)(Sr16 + oiq + p0 + 8 * cg);
        uint4 ub = *(const uint4*)(Sr16 + ojq + p0 + 8 * cg);
        int pb = 8 * cg;
        Rt[RTIDX(pb + 0, qq)] = fmaxf((bf16_lo(ua.x) - bf16_lo(ub.x)) * invr, EPSV);
        Rt[RTIDX(pb + 1, qq)] = fmaxf((bf16_hi(ua.x) - bf16_hi(ub.x)) * invr, EPSV);
        Rt[RTIDX(pb + 2, qq)] = fmaxf((bf16_lo(ua.y) - bf16_lo(ub.y)) * invr, EPSV);
        Rt[RTIDX(pb + 3, qq)] = fmaxf((bf16_hi(ua.y) - bf16_hi(ub.y)) * invr, EPSV);
        Rt[RTIDX(pb + 4, qq)] = fmaxf((bf16_lo(ua.z) - bf16_lo(ub.z)) * invr, EPSV);
        Rt[RTIDX(pb + 5, qq)] = fmaxf((bf16_hi(ua.z) - bf16_hi(ub.z)) * invr, EPSV);
        Rt[RTIDX(pb + 6, qq)] = fmaxf((bf16_lo(ua.w) - bf16_lo(ub.w)) * invr, EPSV);
        Rt[RTIDX(pb + 7, qq)] = fmaxf((bf16_hi(ua.w) - bf16_hi(ub.w)) * invr, EPSV);
    }
    __syncthreads();

    // ---- compute: thread = (pg = t>>3 -> prows {pg, pg+32}) x (qg = t&7 -> 8 q's)
    int qg = t & 7;
    int pg = t >> 3;
    float acc = 0.f;
    #pragma unroll
    for (int pp = 0; pp < 2; ++pp) {
        int prow = pg + 32 * pp;
        int oi = sIp[prow], oj = sJp[prow];
        float invf = sInvF[prow];
        uint4 ua = *(const uint4*)(Sf16 + oi + q0 + 8 * qg);
        uint4 ub = *(const uint4*)(Sf16 + oj + q0 + 8 * qg);
        int base = RTIDX(prow, 8 * qg);
        float4 r0 = *(const float4*)&Rt[base];
        float4 r1 = *(const float4*)&Rt[base + 4];
        acc += fmaxf((bf16_lo(ua.x) - bf16_lo(ub.x)) * invf, EPSV) * r0.x;
        acc += fmaxf((bf16_hi(ua.x) - bf16_hi(ub.x)) * invf, EPSV) * r0.y;
        acc += fmaxf((bf16_lo(ua.y) - bf16_lo(ub.y)) * invf, EPSV) * r0.z;
        acc += fmaxf((bf16_hi(ua.y) - bf16_hi(ub.y)) * invf, EPSV) * r0.w;
        acc += fmaxf((bf16_lo(ua.z) - bf16_lo(ub.z)) * invf, EPSV) * r1.x;
        acc += fmaxf((bf16_hi(ua.z) - bf16_hi(ub.z)) * invf, EPSV) * r1.y;
        acc += fmaxf((bf16_lo(ua.w) - bf16_lo(ub.w)) * invf, EPSV) * r1.z;
        acc += fmaxf((bf16_hi(ua.w) - bf16_hi(ub.w)) * invf, EPSV) * r1.w;
    }

    #pragma unroll
    for (int off = 32; off > 0; off >>= 1) acc += __shfl_down(acc, off, 64);
    int w = t >> 6;
    if ((t & 63) == 0) wsum[w] = acc;
    __syncthreads();
    if (t == 0) partials[blockIdx.y * NT + blockIdx.x] = wsum[0] + wsum[1] + wsum[2] + wsum[3];
}

// ============ fallback norms (proven round-1 path) ============
__global__ void norms_kernel(const float* __restrict__ Sr, const float* __restrict__ Sf,
                             float* __restrict__ inv_nr, float* __restrict__ inv_nf,
                             int* __restrict__ opi, int* __restrict__ opj) {
    int p = blockIdx.x;
    int i = (int)((1.0f + sqrtf(8.0f * (float)p + 1.0f)) * 0.5f);
    while (i * (i - 1) / 2 > p) --i;
    while ((i + 1) * i / 2 <= p) ++i;
    int j = p - i * (i - 1) / 2;

    const float4* ri = (const float4*)(Sr + (size_t)i * D_);
    const float4* rj = (const float4*)(Sr + (size_t)j * D_);
    const float4* fi = (const float4*)(Sf + (size_t)i * D_);
    const float4* fj = (const float4*)(Sf + (size_t)j * D_);

    float sr = 0.f, sf = 0.f;
    for (int d = threadIdx.x; d < D_ / 4; d += 256) {
        float4 a = ri[d], b = rj[d];
        float dx = a.x - b.x, dy = a.y - b.y, dz = a.z - b.z, dw = a.w - b.w;
        sr += dx * dx + dy * dy + dz * dz + dw * dw;
        float4 c2 = fi[d], e = fj[d];
        dx = c2.x - e.x; dy = c2.y - e.y; dz = c2.z - e.z; dw = c2.w - e.w;
        sf += dx * dx + dy * dy + dz * dz + dw * dw;
    }
    #pragma unroll
    for (int off = 32; off > 0; off >>= 1) {
        sr += __shfl_down(sr, off, 64);
        sf += __shfl_down(sf, off, 64);
    }
    __shared__ float wr[4], wf[4];
    int wave = threadIdx.x >> 6;
    if ((threadIdx.x & 63) == 0) { wr[wave] = sr; wf[wave] = sf; }
    __syncthreads();
    if (threadIdx.x == 0) {
        inv_nr[p] = 1.0f / sqrtf(wr[0] + wr[1] + wr[2] + wr[3]);
        inv_nf[p] = 1.0f / sqrtf(wf[0] + wf[1] + wf[2] + wf[3]);
        opi[p] = i * D_;
        opj[p] = j * D_;
    }
}

// ============ fallback fp32 tile (proven round-3 path) ============
__global__ void __launch_bounds__(256, 6)
tile3_kernel(const float* __restrict__ Sr, const float* __restrict__ Sf,
             const float* __restrict__ inv_nr, const float* __restrict__ inv_nf,
             const int* __restrict__ opi, const int* __restrict__ opj,
             float* __restrict__ partials) {
    __shared__ float Rt[64][65];
    __shared__ int   sIp[64], sJp[64];
    __shared__ float sInvF[64];
    __shared__ float wsum[4];

    int t  = threadIdx.x;
    int p0 = blockIdx.x * 64, q0 = blockIdx.y * 64;

    if (t < 64) {
        int p = p0 + t;
        sIp[t]   = opi[p];
        sJp[t]   = opj[p];
        sInvF[t] = inv_nf[p];
    }
    {
        int c  = t & 15;
        int qr = t >> 4;
        #pragma unroll
        for (int pass = 0; pass < 4; ++pass) {
            int qq = qr + 16 * pass;
            int q  = q0 + qq;
            int oi = opi[q], oj = opj[q];
            float invr = inv_nr[q];
            const float4 a = *(const float4*)(Sr + oi + p0 + 4 * c);
            const float4 b = *(const float4*)(Sr + oj + p0 + 4 * c);
            Rt[4 * c + 0][qq] = fmaxf((a.x - b.x) * invr, EPSV);
            Rt[4 * c + 1][qq] = fmaxf((a.y - b.y) * invr, EPSV);
            Rt[4 * c + 2][qq] = fmaxf((a.z - b.z) * invr, EPSV);
            Rt[4 * c + 3][qq] = fmaxf((a.w - b.w) * invr, EPSV);
        }
    }
    __syncthreads();

    int qg = t & 15;
    int pg = t >> 4;
    float ax = 0.f, ay = 0.f, az = 0.f, aw = 0.f;
    #pragma unroll
    for (int pp = 0; pp < 4; ++pp) {
        int prow = pg + 16 * pp;
        int oi = sIp[prow], oj = sJp[prow];
        float invf = sInvF[prow];
        const float4 fa = *(const float4*)(Sf + oi + q0 + 4 * qg);
        const float4 fb = *(const float4*)(Sf + oj + q0 + 4 * qg);
        const float4 r  = *(const float4*)&Rt[prow][4 * qg];
        ax += fmaxf((fa.x - fb.x) * invf, EPSV) * r.x;
        ay += fmaxf((fa.y - fb.y) * invf, EPSV) * r.y;
        az += fmaxf((fa.z - fb.z) * invf, EPSV) * r.z;
        aw += fmaxf((fa.w - fb.w) * invf, EPSV) * r.w;
    }
    float acc = (ax + ay) + (az + aw);

    #pragma unroll
    for (int off = 32; off > 0; off >>= 1) acc += __shfl_down(acc, off, 64);
    int w = t >> 6;
    if ((t & 63) == 0) wsum[w] = acc;
    __syncthreads();
    if (t == 0) partials[blockIdx.y * NT + blockIdx.x] = wsum[0] + wsum[1] + wsum[2] + wsum[3];
}

// ============ final deterministic reduce ============
__global__ void reduce_kernel(const float* __restrict__ partials, int n, float* __restrict__ out) {
    float s = 0.f;
    for (int idx = threadIdx.x; idx < n; idx += 256) s += partials[idx];
    #pragma unroll
    for (int off = 32; off > 0; off >>= 1) s += __shfl_down(s, off, 64);
    __shared__ float wbuf[4];
    int wave = threadIdx.x >> 6;
    if ((threadIdx.x & 63) == 0) wbuf[wave] = s;
    __syncthreads();
    if (threadIdx.x == 0) out[0] = wbuf[0] + wbuf[1] + wbuf[2] + wbuf[3];
}

extern "C" void kernel_launch(void* const* d_in, const int* in_sizes, int n_in,
                              void* d_out, int out_size, void* d_ws, size_t ws_size,
                              hipStream_t stream) {
    const float* Sr = (const float*)d_in[0];
    const float* Sf = (const float*)d_in[1];
    float* out = (float*)d_out;

    // ws layout
    char* w = (char*)d_ws;
    unsigned short* Sr16 = (unsigned short*)w;            w += (size_t)NS * D_ * 2;   // 2.08 MB
    unsigned short* Sf16 = (unsigned short*)w;            w += (size_t)NS * D_ * 2;   // 2.08 MB
    float* inv_nr = (float*)w;                            w += (size_t)P_ * 4;
    float* inv_nf = (float*)w;                            w += (size_t)P_ * 4;
    int*   opi    = (int*)w;                              w += (size_t)P_ * 4;
    int*   opj    = (int*)w;                              w += (size_t)P_ * 4;
    float* tpart  = (float*)w;                            w += (size_t)NT * NT * 4;
    float* npart  = (float*)w;                            w += (size_t)2 * CH * P_ * 4; // 8.26 MB
    size_t need = (size_t)(w - (char*)d_ws);

    if (ws_size >= need) {
        cvt_bf16<<<2 * NS * D_ / 4 / 256, 256, 0, stream>>>(Sr, Sf, Sr16, Sf16);
        dim3 ng(CH, 2);
        norm_partial<<<ng, 512, 0, stream>>>(Sr, Sf, npart);
        norm_finish<<<32, 256, 0, stream>>>(npart, inv_nr, inv_nf, opi, opj);
        dim3 grid(NT, NT);
        tile4_kernel<<<grid, 256, 0, stream>>>(Sr16, Sf16, inv_nr, inv_nf, opi, opj, tpart);
    } else {
        norms_kernel<<<P_, 256, 0, stream>>>(Sr, Sf, inv_nr, inv_nf, opi, opj);
        dim3 grid(NT, NT);
        tile3_kernel<<<grid, 256, 0, stream>>>(Sr, Sf, inv_nr, inv_nf, opi, opj, tpart);
    }
    reduce_kernel<<<1, 256, 0, stream>>>(tpart, NT * NT, out);
}

// Round 5
// 76.645 us; speedup vs baseline: 1.2229x; 1.2229x over previous
//
#include <hip/hip_runtime.h>

#define NS   128          // samples
#define D_   8128         // feature dim
#define P_   8128         // pairs
#define EPSV 1e-12f
#define NT   127          // 8128 / 64 tiles
#define KSPLIT 16         // gram k-slices (254 k-steps of 32 split 16/16/../14)

typedef __attribute__((ext_vector_type(8))) short short8;
typedef __attribute__((ext_vector_type(4))) float f32x4;

// ---- bf16 helpers (top 16 bits of f32, RNE) ----
static __device__ __forceinline__ unsigned short f32_to_bf16_rne(float f) {
    unsigned int u = __float_as_uint(f);
    return (unsigned short)((u + 0x7fffu + ((u >> 16) & 1u)) >> 16);
}
static __device__ __forceinline__ float bf16_lo(unsigned int u) { return __uint_as_float(u << 16); }
static __device__ __forceinline__ float bf16_hi(unsigned int u) { return __uint_as_float(u & 0xffff0000u); }

// Rt LDS addressing for tile kernel: stride 68, q-octet XOR swizzle
__device__ __forceinline__ int RTIDX(int p, int q) {
    return p * 68 + 8 * (((q) >> 3) ^ ((p >> 3) & 7)) + (q & 7);
}

// ============ kernel A: fp32 -> bf16 copies ============
__global__ void cvt_bf16(const float* __restrict__ Sr, const float* __restrict__ Sf,
                         unsigned short* __restrict__ Sr16, unsigned short* __restrict__ Sf16) {
    int tid = blockIdx.x * 256 + threadIdx.x;
    const int half = NS * D_ / 4;                    // 260096 float4s per matrix
    const float* src = (tid < half) ? Sr : Sf;
    unsigned short* dst = (tid < half) ? Sr16 : Sf16;
    int e = (tid < half) ? tid : tid - half;
    float4 v = *(const float4*)(src + 4 * (size_t)e);
    ushort4 o;
    o.x = f32_to_bf16_rne(v.x);
    o.y = f32_to_bf16_rne(v.y);
    o.z = f32_to_bf16_rne(v.z);
    o.w = f32_to_bf16_rne(v.w);
    *(ushort4*)(dst + 4 * (size_t)e) = o;
}

// ============ kernel B: Gram via bf16 MFMA, split-K ============
// grid (KSPLIT, 2), 256 thr = 4 waves. Wave w owns output rows 32w..32w+31
// (2 frag-rows x 8 frag-cols). G symmetric -> layout transposes are harmless.
__global__ void __launch_bounds__(256)
gram_mfma(const unsigned short* __restrict__ Sr16, const unsigned short* __restrict__ Sf16,
          float* __restrict__ Gpart) {
    int sl = blockIdx.x;          // k-slice
    int m  = blockIdx.y;          // 0 = real, 1 = fake
    const unsigned short* __restrict__ S = m ? Sf16 : Sr16;
    float* __restrict__ out = Gpart + ((size_t)sl * 2 + m) * (NS * NS);

    __shared__ short St[128 * 40];   // [row][k], stride 40 bf16 = 80 B (16B-aligned, 2-way banks)

    int t = threadIdx.x;
    int w = t >> 6, l = t & 63;
    int lr = l & 15;                 // fragment row/col lane index
    int kf = (l >> 4) * 8;           // fragment k offset

    int ks_begin = sl * 16;
    int ks_end   = (ks_begin + 16 < 254) ? ks_begin + 16 : 254;

    f32x4 acc[2][8];
    #pragma unroll
    for (int fr = 0; fr < 2; ++fr)
        #pragma unroll
        for (int c = 0; c < 8; ++c) acc[fr][c] = (f32x4)0.f;

    for (int ks = ks_begin; ks < ks_end; ++ks) {
        int k0 = ks * 32;
        // stage 128x32 bf16: 512 b128 tasks, 2 per thread
        #pragma unroll
        for (int g = 0; g < 2; ++g) {
            int task = t + 256 * g;
            int row = task >> 2, kg = task & 3;
            *(short8*)&St[row * 40 + 8 * kg] =
                *(const short8*)(S + (size_t)row * D_ + k0 + 8 * kg);
        }
        __syncthreads();

        short8 a0 = *(const short8*)&St[(w * 32 + lr) * 40 + kf];
        short8 a1 = *(const short8*)&St[(w * 32 + 16 + lr) * 40 + kf];
        #pragma unroll
        for (int c = 0; c < 8; ++c) {
            short8 b = *(const short8*)&St[(c * 16 + lr) * 40 + kf];
            acc[0][c] = __builtin_amdgcn_mfma_f32_16x16x32_bf16(a0, b, acc[0][c], 0, 0, 0);
            acc[1][c] = __builtin_amdgcn_mfma_f32_16x16x32_bf16(a1, b, acc[1][c], 0, 0, 0);
        }
        __syncthreads();
    }

    // C/D: col = lane&15, row = (lane>>4)*4 + reg (within 16x16 frag)
    #pragma unroll
    for (int fr = 0; fr < 2; ++fr) {
        int rbase = w * 32 + fr * 16 + (l >> 4) * 4;
        #pragma unroll
        for (int c = 0; c < 8; ++c) {
            int col = c * 16 + lr;
            #pragma unroll
            for (int r = 0; r < 4; ++r)
                out[(rbase + r) * NS + col] = acc[fr][c][r];
        }
    }
}

// ============ kernel C: pair metadata + inverse norms from Gram partials ============
__global__ void norm_finish(const float* __restrict__ Gpart,
                            float* __restrict__ inv_nr, float* __restrict__ inv_nf,
                            int* __restrict__ opi, int* __restrict__ opj) {
    int p = blockIdx.x * 256 + threadIdx.x;
    if (p >= P_) return;
    int i = (int)((1.0f + sqrtf(8.0f * (float)p + 1.0f)) * 0.5f);
    while (i * (i - 1) / 2 > p) --i;
    while ((i + 1) * i / 2 <= p) ++i;
    int j = p - i * (i - 1) / 2;

    float rii = 0.f, rjj = 0.f, rij = 0.f;
    float fii = 0.f, fjj = 0.f, fij = 0.f;
    #pragma unroll 4
    for (int s = 0; s < KSPLIT; ++s) {
        const float* g0 = Gpart + ((size_t)s * 2 + 0) * (NS * NS);
        const float* g1 = Gpart + ((size_t)s * 2 + 1) * (NS * NS);
        rii += g0[i * NS + i]; rjj += g0[j * NS + j]; rij += g0[i * NS + j];
        fii += g1[i * NS + i]; fjj += g1[j * NS + j]; fij += g1[i * NS + j];
    }
    inv_nr[p] = rsqrtf(fmaxf(rii + rjj - 2.f * rij, 1e-30f));
    inv_nf[p] = rsqrtf(fmaxf(fii + fjj - 2.f * fij, 1e-30f));
    opi[p] = i * D_;
    opj[p] = j * D_;
}

// ============ kernel D: bf16 tile product (unchanged from round 4, passed) ============
__global__ void __launch_bounds__(256, 6)
tile4_kernel(const unsigned short* __restrict__ Sr16, const unsigned short* __restrict__ Sf16,
             const float* __restrict__ inv_nr, const float* __restrict__ inv_nf,
             const int* __restrict__ opi, const int* __restrict__ opj,
             float* __restrict__ partials) {
    __shared__ float Rt[64 * 68];
    __shared__ int   sIp[64], sJp[64];
    __shared__ float sInvF[64];
    __shared__ float wsum[4];

    int t  = threadIdx.x;
    int p0 = blockIdx.x * 64, q0 = blockIdx.y * 64;

    if (t < 64) {
        int p = p0 + t;
        sIp[t]   = opi[p];
        sJp[t]   = opj[p];
        sInvF[t] = inv_nf[p];
    }

    #pragma unroll
    for (int pass = 0; pass < 2; ++pass) {
        int task = t + 256 * pass;
        int qq = task >> 3, cg = task & 7;
        int q  = q0 + qq;
        int oiq = opi[q], ojq = opj[q];
        float invr = inv_nr[q];
        uint4 ua = *(const uint4*)(Sr16 + oiq + p0 + 8 * cg);
        uint4 ub = *(const uint4*)(Sr16 + ojq + p0 + 8 * cg);
        int pb = 8 * cg;
        Rt[RTIDX(pb + 0, qq)] = fmaxf((bf16_lo(ua.x) - bf16_lo(ub.x)) * invr, EPSV);
        Rt[RTIDX(pb + 1, qq)] = fmaxf((bf16_hi(ua.x) - bf16_hi(ub.x)) * invr, EPSV);
        Rt[RTIDX(pb + 2, qq)] = fmaxf((bf16_lo(ua.y) - bf16_lo(ub.y)) * invr, EPSV);
        Rt[RTIDX(pb + 3, qq)] = fmaxf((bf16_hi(ua.y) - bf16_hi(ub.y)) * invr, EPSV);
        Rt[RTIDX(pb + 4, qq)] = fmaxf((bf16_lo(ua.z) - bf16_lo(ub.z)) * invr, EPSV);
        Rt[RTIDX(pb + 5, qq)] = fmaxf((bf16_hi(ua.z) - bf16_hi(ub.z)) * invr, EPSV);
        Rt[RTIDX(pb + 6, qq)] = fmaxf((bf16_lo(ua.w) - bf16_lo(ub.w)) * invr, EPSV);
        Rt[RTIDX(pb + 7, qq)] = fmaxf((bf16_hi(ua.w) - bf16_hi(ub.w)) * invr, EPSV);
    }
    __syncthreads();

    int qg = t & 7;
    int pg = t >> 3;
    float acc = 0.f;
    #pragma unroll
    for (int pp = 0; pp < 2; ++pp) {
        int prow = pg + 32 * pp;
        int oi = sIp[prow], oj = sJp[prow];
        float invf = sInvF[prow];
        uint4 ua = *(const uint4*)(Sf16 + oi + q0 + 8 * qg);
        uint4 ub = *(const uint4*)(Sf16 + oj + q0 + 8 * qg);
        int base = RTIDX(prow, 8 * qg);
        float4 r0 = *(const float4*)&Rt[base];
        float4 r1 = *(const float4*)&Rt[base + 4];
        acc += fmaxf((bf16_lo(ua.x) - bf16_lo(ub.x)) * invf, EPSV) * r0.x;
        acc += fmaxf((bf16_hi(ua.x) - bf16_hi(ub.x)) * invf, EPSV) * r0.y;
        acc += fmaxf((bf16_lo(ua.y) - bf16_lo(ub.y)) * invf, EPSV) * r0.z;
        acc += fmaxf((bf16_hi(ua.y) - bf16_hi(ub.y)) * invf, EPSV) * r0.w;
        acc += fmaxf((bf16_lo(ua.z) - bf16_lo(ub.z)) * invf, EPSV) * r1.x;
        acc += fmaxf((bf16_hi(ua.z) - bf16_hi(ub.z)) * invf, EPSV) * r1.y;
        acc += fmaxf((bf16_lo(ua.w) - bf16_lo(ub.w)) * invf, EPSV) * r1.z;
        acc += fmaxf((bf16_hi(ua.w) - bf16_hi(ub.w)) * invf, EPSV) * r1.w;
    }

    #pragma unroll
    for (int off = 32; off > 0; off >>= 1) acc += __shfl_down(acc, off, 64);
    int w = t >> 6;
    if ((t & 63) == 0) wsum[w] = acc;
    __syncthreads();
    if (t == 0) partials[blockIdx.y * NT + blockIdx.x] = wsum[0] + wsum[1] + wsum[2] + wsum[3];
}

// ============ fallback norms + fp32 tile (proven round-1/3 path) ============
__global__ void norms_kernel(const float* __restrict__ Sr, const float* __restrict__ Sf,
                             float* __restrict__ inv_nr, float* __restrict__ inv_nf,
                             int* __restrict__ opi, int* __restrict__ opj) {
    int p = blockIdx.x;
    int i = (int)((1.0f + sqrtf(8.0f * (float)p + 1.0f)) * 0.5f);
    while (i * (i - 1) / 2 > p) --i;
    while ((i + 1) * i / 2 <= p) ++i;
    int j = p - i * (i - 1) / 2;

    const float4* ri = (const float4*)(Sr + (size_t)i * D_);
    const float4* rj = (const float4*)(Sr + (size_t)j * D_);
    const float4* fi = (const float4*)(Sf + (size_t)i * D_);
    const float4* fj = (const float4*)(Sf + (size_t)j * D_);

    float sr = 0.f, sf = 0.f;
    for (int d = threadIdx.x; d < D_ / 4; d += 256) {
        float4 a = ri[d], b = rj[d];
        float dx = a.x - b.x, dy = a.y - b.y, dz = a.z - b.z, dw = a.w - b.w;
        sr += dx * dx + dy * dy + dz * dz + dw * dw;
        float4 c2 = fi[d], e = fj[d];
        dx = c2.x - e.x; dy = c2.y - e.y; dz = c2.z - e.z; dw = c2.w - e.w;
        sf += dx * dx + dy * dy + dz * dz + dw * dw;
    }
    #pragma unroll
    for (int off = 32; off > 0; off >>= 1) {
        sr += __shfl_down(sr, off, 64);
        sf += __shfl_down(sf, off, 64);
    }
    __shared__ float wr[4], wf[4];
    int wave = threadIdx.x >> 6;
    if ((threadIdx.x & 63) == 0) { wr[wave] = sr; wf[wave] = sf; }
    __syncthreads();
    if (threadIdx.x == 0) {
        inv_nr[p] = 1.0f / sqrtf(wr[0] + wr[1] + wr[2] + wr[3]);
        inv_nf[p] = 1.0f / sqrtf(wf[0] + wf[1] + wf[2] + wf[3]);
        opi[p] = i * D_;
        opj[p] = j * D_;
    }
}

__global__ void __launch_bounds__(256, 6)
tile3_kernel(const float* __restrict__ Sr, const float* __restrict__ Sf,
             const float* __restrict__ inv_nr, const float* __restrict__ inv_nf,
             const int* __restrict__ opi, const int* __restrict__ opj,
             float* __restrict__ partials) {
    __shared__ float Rt[64][65];
    __shared__ int   sIp[64], sJp[64];
    __shared__ float sInvF[64];
    __shared__ float wsum[4];

    int t  = threadIdx.x;
    int p0 = blockIdx.x * 64, q0 = blockIdx.y * 64;

    if (t < 64) {
        int p = p0 + t;
        sIp[t]   = opi[p];
        sJp[t]   = opj[p];
        sInvF[t] = inv_nf[p];
    }
    {
        int c  = t & 15;
        int qr = t >> 4;
        #pragma unroll
        for (int pass = 0; pass < 4; ++pass) {
            int qq = qr + 16 * pass;
            int q  = q0 + qq;
            int oi = opi[q], oj = opj[q];
            float invr = inv_nr[q];
            const float4 a = *(const float4*)(Sr + oi + p0 + 4 * c);
            const float4 b = *(const float4*)(Sr + oj + p0 + 4 * c);
            Rt[4 * c + 0][qq] = fmaxf((a.x - b.x) * invr, EPSV);
            Rt[4 * c + 1][qq] = fmaxf((a.y - b.y) * invr, EPSV);
            Rt[4 * c + 2][qq] = fmaxf((a.z - b.z) * invr, EPSV);
            Rt[4 * c + 3][qq] = fmaxf((a.w - b.w) * invr, EPSV);
        }
    }
    __syncthreads();

    int qg = t & 15;
    int pg = t >> 4;
    float ax = 0.f, ay = 0.f, az = 0.f, aw = 0.f;
    #pragma unroll
    for (int pp = 0; pp < 4; ++pp) {
        int prow = pg + 16 * pp;
        int oi = sIp[prow], oj = sJp[prow];
        float invf = sInvF[prow];
        const float4 fa = *(const float4*)(Sf + oi + q0 + 4 * qg);
        const float4 fb = *(const float4*)(Sf + oj + q0 + 4 * qg);
        const float4 r  = *(const float4*)&Rt[prow][4 * qg];
        ax += fmaxf((fa.x - fb.x) * invf, EPSV) * r.x;
        ay += fmaxf((fa.y - fb.y) * invf, EPSV) * r.y;
        az += fmaxf((fa.z - fb.z) * invf, EPSV) * r.z;
        aw += fmaxf((fa.w - fb.w) * invf, EPSV) * r.w;
    }
    float acc = (ax + ay) + (az + aw);

    #pragma unroll
    for (int off = 32; off > 0; off >>= 1) acc += __shfl_down(acc, off, 64);
    int w = t >> 6;
    if ((t & 63) == 0) wsum[w] = acc;
    __syncthreads();
    if (t == 0) partials[blockIdx.y * NT + blockIdx.x] = wsum[0] + wsum[1] + wsum[2] + wsum[3];
}

// ============ final deterministic reduce ============
__global__ void reduce_kernel(const float* __restrict__ partials, int n, float* __restrict__ out) {
    float s = 0.f;
    for (int idx = threadIdx.x; idx < n; idx += 256) s += partials[idx];
    #pragma unroll
    for (int off = 32; off > 0; off >>= 1) s += __shfl_down(s, off, 64);
    __shared__ float wbuf[4];
    int wave = threadIdx.x >> 6;
    if ((threadIdx.x & 63) == 0) wbuf[wave] = s;
    __syncthreads();
    if (threadIdx.x == 0) out[0] = wbuf[0] + wbuf[1] + wbuf[2] + wbuf[3];
}

extern "C" void kernel_launch(void* const* d_in, const int* in_sizes, int n_in,
                              void* d_out, int out_size, void* d_ws, size_t ws_size,
                              hipStream_t stream) {
    const float* Sr = (const float*)d_in[0];
    const float* Sf = (const float*)d_in[1];
    float* out = (float*)d_out;

    // ws layout
    char* w = (char*)d_ws;
    unsigned short* Sr16 = (unsigned short*)w;            w += (size_t)NS * D_ * 2;          // 2.08 MB
    unsigned short* Sf16 = (unsigned short*)w;            w += (size_t)NS * D_ * 2;          // 2.08 MB
    float* inv_nr = (float*)w;                            w += (size_t)P_ * 4;
    float* inv_nf = (float*)w;                            w += (size_t)P_ * 4;
    int*   opi    = (int*)w;                              w += (size_t)P_ * 4;
    int*   opj    = (int*)w;                              w += (size_t)P_ * 4;
    float* tpart  = (float*)w;                            w += (size_t)NT * NT * 4;
    float* Gpart  = (float*)w;                            w += (size_t)KSPLIT * 2 * NS * NS * 4; // 4.2 MB
    size_t need = (size_t)(w - (char*)d_ws);

    if (ws_size >= need) {
        cvt_bf16<<<2 * NS * D_ / 4 / 256, 256, 0, stream>>>(Sr, Sf, Sr16, Sf16);
        dim3 gg(KSPLIT, 2);
        gram_mfma<<<gg, 256, 0, stream>>>(Sr16, Sf16, Gpart);
        norm_finish<<<32, 256, 0, stream>>>(Gpart, inv_nr, inv_nf, opi, opj);
        dim3 grid(NT, NT);
        tile4_kernel<<<grid, 256, 0, stream>>>(Sr16, Sf16, inv_nr, inv_nf, opi, opj, tpart);
    } else {
        norms_kernel<<<P_, 256, 0, stream>>>(Sr, Sf, inv_nr, inv_nf, opi, opj);
        dim3 grid(NT, NT);
        tile3_kernel<<<grid, 256, 0, stream>>>(Sr, Sf, inv_nr, inv_nf, opi, opj, tpart);
    }
    reduce_kernel<<<1, 256, 0, stream>>>(tpart, NT * NT, out);
}

// Round 6
// 68.442 us; speedup vs baseline: 1.3695x; 1.1199x over previous
//
#include <hip/hip_runtime.h>

#define NS   128          // samples
#define D_   8128         // feature dim
#define P_   8128         // pairs
#define EPSV 1e-12f
#define NT   127          // 8128 / 64 tiles
#define KSPLIT 16         // gram k-slices (254 k-steps of 32: 16 per slice, last 14)

typedef __attribute__((ext_vector_type(8))) short short8;
typedef __attribute__((ext_vector_type(4))) float f32x4;

// ---- bf16 helpers (top 16 bits of f32, RNE) ----
static __device__ __forceinline__ unsigned short f32_to_bf16_rne(float f) {
    unsigned int u = __float_as_uint(f);
    return (unsigned short)((u + 0x7fffu + ((u >> 16) & 1u)) >> 16);
}
static __device__ __forceinline__ float bf16_lo(unsigned int u) { return __uint_as_float(u << 16); }
static __device__ __forceinline__ float bf16_hi(unsigned int u) { return __uint_as_float(u & 0xffff0000u); }

// Rt LDS addressing for tile kernel: stride 68, q-octet XOR swizzle
__device__ __forceinline__ int RTIDX(int p, int q) {
    return p * 68 + 8 * (((q) >> 3) ^ ((p >> 3) & 7)) + (q & 7);
}

// ============ K1: fused fp32->bf16 convert + Gram via bf16 MFMA (split-K) ============
// grid (KSPLIT, 2), 256 thr. Each block: one 512-col k-slice of one matrix.
// Stages fp32 -> converts -> LDS (proven round-5 layout) + writes bf16 slice to ws.
__global__ void __launch_bounds__(256)
gram_cvt(const float* __restrict__ Sr, const float* __restrict__ Sf,
         unsigned short* __restrict__ Sr16, unsigned short* __restrict__ Sf16,
         float* __restrict__ Gpart) {
    int sl = blockIdx.x;          // k-slice
    int m  = blockIdx.y;          // 0 = real, 1 = fake
    const float* __restrict__ S = m ? Sf : Sr;
    unsigned short* __restrict__ S16 = m ? Sf16 : Sr16;
    float* __restrict__ out = Gpart + ((size_t)sl * 2 + m) * (NS * NS);

    __shared__ short St[128 * 40];   // [row][k], stride 40 bf16 (proven round 5)

    int t = threadIdx.x;
    int w = t >> 6, l = t & 63;
    int lr = l & 15;
    int kf = (l >> 4) * 8;

    int ks_begin = sl * 16;
    int ks_end   = (ks_begin + 16 < 254) ? ks_begin + 16 : 254;

    f32x4 acc[2][8];
    #pragma unroll
    for (int fr = 0; fr < 2; ++fr)
        #pragma unroll
        for (int c = 0; c < 8; ++c) acc[fr][c] = (f32x4)0.f;

    for (int ks = ks_begin; ks < ks_end; ++ks) {
        int k0 = ks * 32;
        // stage 128 rows x 32 cols: fp32 load -> RNE bf16 -> LDS + global bf16 copy
        #pragma unroll
        for (int g4 = 0; g4 < 4; ++g4) {
            int task = t + 256 * g4;       // 0..1023
            int row  = task >> 3;          // 0..127
            int g    = task & 7;           // cols 4g..4g+3
            float4 v = *(const float4*)(S + (size_t)row * D_ + k0 + 4 * g);
            ushort4 o;
            o.x = f32_to_bf16_rne(v.x);
            o.y = f32_to_bf16_rne(v.y);
            o.z = f32_to_bf16_rne(v.z);
            o.w = f32_to_bf16_rne(v.w);
            *(ushort4*)&St[row * 40 + 4 * g] = o;
            *(ushort4*)(S16 + (size_t)row * D_ + k0 + 4 * g) = o;
        }
        __syncthreads();

        short8 a0 = *(const short8*)&St[(w * 32 + lr) * 40 + kf];
        short8 a1 = *(const short8*)&St[(w * 32 + 16 + lr) * 40 + kf];
        #pragma unroll
        for (int c = 0; c < 8; ++c) {
            short8 b = *(const short8*)&St[(c * 16 + lr) * 40 + kf];
            acc[0][c] = __builtin_amdgcn_mfma_f32_16x16x32_bf16(a0, b, acc[0][c], 0, 0, 0);
            acc[1][c] = __builtin_amdgcn_mfma_f32_16x16x32_bf16(a1, b, acc[1][c], 0, 0, 0);
        }
        __syncthreads();
    }

    // C/D: col = lane&15, row = (lane>>4)*4 + reg (G symmetric -> transpose-safe)
    #pragma unroll
    for (int fr = 0; fr < 2; ++fr) {
        int rbase = w * 32 + fr * 16 + (l >> 4) * 4;
        #pragma unroll
        for (int c = 0; c < 8; ++c) {
            int col = c * 16 + lr;
            #pragma unroll
            for (int r = 0; r < 4; ++r)
                out[(rbase + r) * NS + col] = acc[fr][c][r];
        }
    }
}

// ============ K2: collapse Gram slices (coalesced) ============
__global__ void gram_sum(const float* __restrict__ Gpart, float* __restrict__ G) {
    int idx = blockIdx.x * 256 + threadIdx.x;   // 0..32767
    int m = idx >> 14, e = idx & 16383;
    float s = 0.f;
    #pragma unroll
    for (int sl = 0; sl < KSPLIT; ++sl)
        s += Gpart[((size_t)sl * 2 + m) * (NS * NS) + e];
    G[idx] = s;
}

// ============ K3: pair metadata + inverse norms from G ============
__global__ void norm_finish(const float* __restrict__ G,
                            float* __restrict__ inv_nr, float* __restrict__ inv_nf,
                            int* __restrict__ opi, int* __restrict__ opj) {
    int p = blockIdx.x * 256 + threadIdx.x;
    if (p >= P_) return;
    int i = (int)((1.0f + sqrtf(8.0f * (float)p + 1.0f)) * 0.5f);
    while (i * (i - 1) / 2 > p) --i;
    while ((i + 1) * i / 2 <= p) ++i;
    int j = p - i * (i - 1) / 2;

    const float* Gr = G;
    const float* Gf = G + NS * NS;
    float nr2 = Gr[i * NS + i] + Gr[j * NS + j] - 2.f * Gr[i * NS + j];
    float nf2 = Gf[i * NS + i] + Gf[j * NS + j] - 2.f * Gf[i * NS + j];
    inv_nr[p] = rsqrtf(fmaxf(nr2, 1e-30f));
    inv_nf[p] = rsqrtf(fmaxf(nf2, 1e-30f));
    opi[p] = i * D_;
    opj[p] = j * D_;
}

// ============ K4: tile5 — tile4 strip-mined over 4 q-tiles per block ============
// grid (NT, 32), 256 thr. Block bx owns p-tile bx; loops q-tiles {by, by+32, ...}.
__global__ void __launch_bounds__(256, 8)
tile5_kernel(const unsigned short* __restrict__ Sr16, const unsigned short* __restrict__ Sf16,
             const float* __restrict__ inv_nr, const float* __restrict__ inv_nf,
             const int* __restrict__ opi, const int* __restrict__ opj,
             float* __restrict__ partials) {
    __shared__ float Rt[64 * 68];
    __shared__ int   sIp[64], sJp[64];
    __shared__ float sInvF[64];
    __shared__ float wsum[4];

    int t  = threadIdx.x;
    int p0 = blockIdx.x * 64;

    if (t < 64) {
        int p = p0 + t;
        sIp[t]   = opi[p];
        sJp[t]   = opj[p];
        sInvF[t] = inv_nf[p];
    }

    int qg = t & 7;
    int pg = t >> 3;

    for (int qt = blockIdx.y; qt < NT; qt += 32) {
        int q0 = qt * 64;

        // ---- stage Rt[p][q] = max((Sr[i_q][p]-Sr[j_q][p])*inv_nr[q], eps)
        #pragma unroll
        for (int pass = 0; pass < 2; ++pass) {
            int task = t + 256 * pass;
            int qq = task >> 3, cg = task & 7;
            int q  = q0 + qq;
            int oiq = opi[q], ojq = opj[q];
            float invr = inv_nr[q];
            uint4 ua = *(const uint4*)(Sr16 + oiq + p0 + 8 * cg);
            uint4 ub = *(const uint4*)(Sr16 + ojq + p0 + 8 * cg);
            int pb = 8 * cg;
            Rt[RTIDX(pb + 0, qq)] = fmaxf((bf16_lo(ua.x) - bf16_lo(ub.x)) * invr, EPSV);
            Rt[RTIDX(pb + 1, qq)] = fmaxf((bf16_hi(ua.x) - bf16_hi(ub.x)) * invr, EPSV);
            Rt[RTIDX(pb + 2, qq)] = fmaxf((bf16_lo(ua.y) - bf16_lo(ub.y)) * invr, EPSV);
            Rt[RTIDX(pb + 3, qq)] = fmaxf((bf16_hi(ua.y) - bf16_hi(ub.y)) * invr, EPSV);
            Rt[RTIDX(pb + 4, qq)] = fmaxf((bf16_lo(ua.z) - bf16_lo(ub.z)) * invr, EPSV);
            Rt[RTIDX(pb + 5, qq)] = fmaxf((bf16_hi(ua.z) - bf16_hi(ub.z)) * invr, EPSV);
            Rt[RTIDX(pb + 6, qq)] = fmaxf((bf16_lo(ua.w) - bf16_lo(ub.w)) * invr, EPSV);
            Rt[RTIDX(pb + 7, qq)] = fmaxf((bf16_hi(ua.w) - bf16_hi(ub.w)) * invr, EPSV);
        }
        __syncthreads();

        // ---- compute: thread = prows {pg, pg+32} x 8 q's
        float acc = 0.f;
        #pragma unroll
        for (int pp = 0; pp < 2; ++pp) {
            int prow = pg + 32 * pp;
            int oi = sIp[prow], oj = sJp[prow];
            float invf = sInvF[prow];
            uint4 ua = *(const uint4*)(Sf16 + oi + q0 + 8 * qg);
            uint4 ub = *(const uint4*)(Sf16 + oj + q0 + 8 * qg);
            int base = RTIDX(prow, 8 * qg);
            float4 r0 = *(const float4*)&Rt[base];
            float4 r1 = *(const float4*)&Rt[base + 4];
            acc += fmaxf((bf16_lo(ua.x) - bf16_lo(ub.x)) * invf, EPSV) * r0.x;
            acc += fmaxf((bf16_hi(ua.x) - bf16_hi(ub.x)) * invf, EPSV) * r0.y;
            acc += fmaxf((bf16_lo(ua.y) - bf16_lo(ub.y)) * invf, EPSV) * r0.z;
            acc += fmaxf((bf16_hi(ua.y) - bf16_hi(ub.y)) * invf, EPSV) * r0.w;
            acc += fmaxf((bf16_lo(ua.z) - bf16_lo(ub.z)) * invf, EPSV) * r1.x;
            acc += fmaxf((bf16_hi(ua.z) - bf16_hi(ub.z)) * invf, EPSV) * r1.y;
            acc += fmaxf((bf16_lo(ua.w) - bf16_lo(ub.w)) * invf, EPSV) * r1.z;
            acc += fmaxf((bf16_hi(ua.w) - bf16_hi(ub.w)) * invf, EPSV) * r1.w;
        }

        #pragma unroll
        for (int off = 32; off > 0; off >>= 1) acc += __shfl_down(acc, off, 64);
        if ((t & 63) == 0) wsum[t >> 6] = acc;
        __syncthreads();
        if (t == 0) partials[qt * NT + blockIdx.x] = wsum[0] + wsum[1] + wsum[2] + wsum[3];
        // next iteration's post-stage barrier orders Rt/wsum reuse
    }
}

// ============ fallback norms + fp32 tile (proven round-1/3 path) ============
__global__ void norms_kernel(const float* __restrict__ Sr, const float* __restrict__ Sf,
                             float* __restrict__ inv_nr, float* __restrict__ inv_nf,
                             int* __restrict__ opi, int* __restrict__ opj) {
    int p = blockIdx.x;
    int i = (int)((1.0f + sqrtf(8.0f * (float)p + 1.0f)) * 0.5f);
    while (i * (i - 1) / 2 > p) --i;
    while ((i + 1) * i / 2 <= p) ++i;
    int j = p - i * (i - 1) / 2;

    const float4* ri = (const float4*)(Sr + (size_t)i * D_);
    const float4* rj = (const float4*)(Sr + (size_t)j * D_);
    const float4* fi = (const float4*)(Sf + (size_t)i * D_);
    const float4* fj = (const float4*)(Sf + (size_t)j * D_);

    float sr = 0.f, sf = 0.f;
    for (int d = threadIdx.x; d < D_ / 4; d += 256) {
        float4 a = ri[d], b = rj[d];
        float dx = a.x - b.x, dy = a.y - b.y, dz = a.z - b.z, dw = a.w - b.w;
        sr += dx * dx + dy * dy + dz * dz + dw * dw;
        float4 c2 = fi[d], e = fj[d];
        dx = c2.x - e.x; dy = c2.y - e.y; dz = c2.z - e.z; dw = c2.w - e.w;
        sf += dx * dx + dy * dy + dz * dz + dw * dw;
    }
    #pragma unroll
    for (int off = 32; off > 0; off >>= 1) {
        sr += __shfl_down(sr, off, 64);
        sf += __shfl_down(sf, off, 64);
    }
    __shared__ float wr[4], wf[4];
    int wave = threadIdx.x >> 6;
    if ((threadIdx.x & 63) == 0) { wr[wave] = sr; wf[wave] = sf; }
    __syncthreads();
    if (threadIdx.x == 0) {
        inv_nr[p] = 1.0f / sqrtf(wr[0] + wr[1] + wr[2] + wr[3]);
        inv_nf[p] = 1.0f / sqrtf(wf[0] + wf[1] + wf[2] + wf[3]);
        opi[p] = i * D_;
        opj[p] = j * D_;
    }
}

__global__ void __launch_bounds__(256, 6)
tile3_kernel(const float* __restrict__ Sr, const float* __restrict__ Sf,
             const float* __restrict__ inv_nr, const float* __restrict__ inv_nf,
             const int* __restrict__ opi, const int* __restrict__ opj,
             float* __restrict__ partials) {
    __shared__ float Rt[64][65];
    __shared__ int   sIp[64], sJp[64];
    __shared__ float sInvF[64];
    __shared__ float wsum[4];

    int t  = threadIdx.x;
    int p0 = blockIdx.x * 64, q0 = blockIdx.y * 64;

    if (t < 64) {
        int p = p0 + t;
        sIp[t]   = opi[p];
        sJp[t]   = opj[p];
        sInvF[t] = inv_nf[p];
    }
    {
        int c  = t & 15;
        int qr = t >> 4;
        #pragma unroll
        for (int pass = 0; pass < 4; ++pass) {
            int qq = qr + 16 * pass;
            int q  = q0 + qq;
            int oi = opi[q], oj = opj[q];
            float invr = inv_nr[q];
            const float4 a = *(const float4*)(Sr + oi + p0 + 4 * c);
            const float4 b = *(const float4*)(Sr + oj + p0 + 4 * c);
            Rt[4 * c + 0][qq] = fmaxf((a.x - b.x) * invr, EPSV);
            Rt[4 * c + 1][qq] = fmaxf((a.y - b.y) * invr, EPSV);
            Rt[4 * c + 2][qq] = fmaxf((a.z - b.z) * invr, EPSV);
            Rt[4 * c + 3][qq] = fmaxf((a.w - b.w) * invr, EPSV);
        }
    }
    __syncthreads();

    int qg = t & 15;
    int pg = t >> 4;
    float ax = 0.f, ay = 0.f, az = 0.f, aw = 0.f;
    #pragma unroll
    for (int pp = 0; pp < 4; ++pp) {
        int prow = pg + 16 * pp;
        int oi = sIp[prow], oj = sJp[prow];
        float invf = sInvF[prow];
        const float4 fa = *(const float4*)(Sf + oi + q0 + 4 * qg);
        const float4 fb = *(const float4*)(Sf + oj + q0 + 4 * qg);
        const float4 r  = *(const float4*)&Rt[prow][4 * qg];
        ax += fmaxf((fa.x - fb.x) * invf, EPSV) * r.x;
        ay += fmaxf((fa.y - fb.y) * invf, EPSV) * r.y;
        az += fmaxf((fa.z - fb.z) * invf, EPSV) * r.z;
        aw += fmaxf((fa.w - fb.w) * invf, EPSV) * r.w;
    }
    float acc = (ax + ay) + (az + aw);

    #pragma unroll
    for (int off = 32; off > 0; off >>= 1) acc += __shfl_down(acc, off, 64);
    int w = t >> 6;
    if ((t & 63) == 0) wsum[w] = acc;
    __syncthreads();
    if (t == 0) partials[blockIdx.y * NT + blockIdx.x] = wsum[0] + wsum[1] + wsum[2] + wsum[3];
}

// ============ K5: final deterministic reduce (1024 thr) ============
__global__ void reduce_kernel(const float* __restrict__ partials, int n, float* __restrict__ out) {
    float s = 0.f;
    for (int idx = threadIdx.x; idx < n; idx += 1024) s += partials[idx];
    #pragma unroll
    for (int off = 32; off > 0; off >>= 1) s += __shfl_down(s, off, 64);
    __shared__ float wbuf[16];
    int wave = threadIdx.x >> 6;
    if ((threadIdx.x & 63) == 0) wbuf[wave] = s;
    __syncthreads();
    if (threadIdx.x == 0) {
        float tot = 0.f;
        #pragma unroll
        for (int k = 0; k < 16; ++k) tot += wbuf[k];
        out[0] = tot;
    }
}

extern "C" void kernel_launch(void* const* d_in, const int* in_sizes, int n_in,
                              void* d_out, int out_size, void* d_ws, size_t ws_size,
                              hipStream_t stream) {
    const float* Sr = (const float*)d_in[0];
    const float* Sf = (const float*)d_in[1];
    float* out = (float*)d_out;

    // ws layout
    char* w = (char*)d_ws;
    unsigned short* Sr16 = (unsigned short*)w;   w += (size_t)NS * D_ * 2;              // 2.08 MB
    unsigned short* Sf16 = (unsigned short*)w;   w += (size_t)NS * D_ * 2;              // 2.08 MB
    float* inv_nr = (float*)w;                   w += (size_t)P_ * 4;
    float* inv_nf = (float*)w;                   w += (size_t)P_ * 4;
    int*   opi    = (int*)w;                     w += (size_t)P_ * 4;
    int*   opj    = (int*)w;                     w += (size_t)P_ * 4;
    float* tpart  = (float*)w;                   w += (size_t)NT * NT * 4;
    float* Gpart  = (float*)w;                   w += (size_t)KSPLIT * 2 * NS * NS * 4; // 4.2 MB
    float* G      = (float*)w;                   w += (size_t)2 * NS * NS * 4;          // 131 KB
    size_t need = (size_t)(w - (char*)d_ws);

    if (ws_size >= need) {
        dim3 gg(KSPLIT, 2);
        gram_cvt<<<gg, 256, 0, stream>>>(Sr, Sf, Sr16, Sf16, Gpart);
        gram_sum<<<128, 256, 0, stream>>>(Gpart, G);
        norm_finish<<<32, 256, 0, stream>>>(G, inv_nr, inv_nf, opi, opj);
        dim3 grid(NT, 32);
        tile5_kernel<<<grid, 256, 0, stream>>>(Sr16, Sf16, inv_nr, inv_nf, opi, opj, tpart);
    } else {
        norms_kernel<<<P_, 256, 0, stream>>>(Sr, Sf, inv_nr, inv_nf, opi, opj);
        dim3 grid(NT, NT);
        tile3_kernel<<<grid, 256, 0, stream>>>(Sr, Sf, inv_nr, inv_nf, opi, opj, tpart);
    }
    reduce_kernel<<<1, 1024, 0, stream>>>(tpart, NT * NT, out);
}

// Round 8
// 62.447 us; speedup vs baseline: 1.5009x; 1.0960x over previous
//
#include <hip/hip_runtime.h>

#define NS   128          // samples
#define D_   8128         // feature dim (physical)
#define DP_  8192         // padded feature stride for bf16 copies (cols 8128..8191 zeroed)
#define P_   8128         // real pairs
#define PP   8192         // padded pairs (pad entries: inv=0 -> value=eps, negligible)
#define EPSV 1e-12f
#define NT   127          // fallback: 8128/64 tiles
#define KSPLIT 64         // gram k-slices (254 k-steps of 32: 4 per slice, last gets 2)

typedef __attribute__((ext_vector_type(8))) short short8;
typedef __attribute__((ext_vector_type(4))) float f32x4;

// ---- bf16 helpers (top 16 bits of f32, RNE) ----
static __device__ __forceinline__ unsigned short f32_to_bf16_rne(float f) {
    unsigned int u = __float_as_uint(f);
    return (unsigned short)((u + 0x7fffu + ((u >> 16) & 1u)) >> 16);
}
static __device__ __forceinline__ float bf16_lo(unsigned int u) { return __uint_as_float(u << 16); }
static __device__ __forceinline__ float bf16_hi(unsigned int u) { return __uint_as_float(u & 0xffff0000u); }

// ============ K0: zero the pad columns [8128,8192) of both bf16 matrices ============
__global__ void pad_zero(unsigned short* __restrict__ Sr16, unsigned short* __restrict__ Sf16) {
    int e = blockIdx.x * 256 + threadIdx.x;     // 0..2047 uint4s (8 ushorts each)
    int mtx = e >> 10;                          // 1024 uint4 per matrix (128 rows x 8)
    int rem = e & 1023;
    int row = rem >> 3;
    int c4  = rem & 7;                          // pad col group: 8128 + 8*c4
    unsigned short* dst = (mtx ? Sf16 : Sr16) + (size_t)row * DP_ + D_ + 8 * c4;
    uint4 z; z.x = 0u; z.y = 0u; z.z = 0u; z.w = 0u;
    *(uint4*)dst = z;
}

// ============ K1: fused fp32->bf16 convert + Gram via bf16 MFMA (split-K) ============
// grid (KSPLIT, 2), 256 thr. Slice sl covers k-steps [4sl, min(4sl+4,254)).
__global__ void __launch_bounds__(256)
gram_cvt(const float* __restrict__ Sr, const float* __restrict__ Sf,
         unsigned short* __restrict__ Sr16, unsigned short* __restrict__ Sf16,
         float* __restrict__ Gpart) {
    int sl = blockIdx.x;
    int m  = blockIdx.y;
    const float* __restrict__ S = m ? Sf : Sr;
    unsigned short* __restrict__ S16 = m ? Sf16 : Sr16;
    float* __restrict__ out = Gpart + ((size_t)sl * 2 + m) * (NS * NS);

    __shared__ short St[128 * 40];   // [row][k], stride 40 bf16 (proven layout)

    int t = threadIdx.x;
    int w = t >> 6, l = t & 63;
    int lr = l & 15;
    int kf = (l >> 4) * 8;

    int ks_begin = sl * 4;
    int ks_end   = (ks_begin + 4 < 254) ? ks_begin + 4 : 254;

    f32x4 acc[2][8];
    #pragma unroll
    for (int fr = 0; fr < 2; ++fr)
        #pragma unroll
        for (int c = 0; c < 8; ++c) acc[fr][c] = (f32x4)0.f;

    for (int ks = ks_begin; ks < ks_end; ++ks) {
        int k0 = ks * 32;
        #pragma unroll
        for (int g4 = 0; g4 < 4; ++g4) {
            int task = t + 256 * g4;       // 0..1023
            int row  = task >> 3;          // 0..127
            int g    = task & 7;           // cols 4g..4g+3
            float4 v = *(const float4*)(S + (size_t)row * D_ + k0 + 4 * g);
            ushort4 o;
            o.x = f32_to_bf16_rne(v.x);
            o.y = f32_to_bf16_rne(v.y);
            o.z = f32_to_bf16_rne(v.z);
            o.w = f32_to_bf16_rne(v.w);
            *(ushort4*)&St[row * 40 + 4 * g] = o;
            *(ushort4*)(S16 + (size_t)row * DP_ + k0 + 4 * g) = o;   // padded stride
        }
        __syncthreads();

        short8 a0 = *(const short8*)&St[(w * 32 + lr) * 40 + kf];
        short8 a1 = *(const short8*)&St[(w * 32 + 16 + lr) * 40 + kf];
        #pragma unroll
        for (int c = 0; c < 8; ++c) {
            short8 b = *(const short8*)&St[(c * 16 + lr) * 40 + kf];
            acc[0][c] = __builtin_amdgcn_mfma_f32_16x16x32_bf16(a0, b, acc[0][c], 0, 0, 0);
            acc[1][c] = __builtin_amdgcn_mfma_f32_16x16x32_bf16(a1, b, acc[1][c], 0, 0, 0);
        }
        __syncthreads();
    }

    #pragma unroll
    for (int fr = 0; fr < 2; ++fr) {
        int rbase = w * 32 + fr * 16 + (l >> 4) * 4;
        #pragma unroll
        for (int c = 0; c < 8; ++c) {
            int col = c * 16 + lr;
            #pragma unroll
            for (int r = 0; r < 4; ++r)
                out[(rbase + r) * NS + col] = acc[fr][c][r];
        }
    }
}

// ============ K2: collapse Gram slices (coalesced) ============
__global__ void gram_sum(const float* __restrict__ Gpart, float* __restrict__ G) {
    int idx = blockIdx.x * 256 + threadIdx.x;   // 0..32767
    int m = idx >> 14, e = idx & 16383;
    float s = 0.f;
    #pragma unroll 8
    for (int sl = 0; sl < KSPLIT; ++sl)
        s += Gpart[((size_t)sl * 2 + m) * (NS * NS) + e];
    G[idx] = s;
}

// ============ K3: pair metadata + inverse norms (padded to PP; offsets use DP_) ====
__global__ void norm_finish(const float* __restrict__ G,
                            float* __restrict__ inv_nr, float* __restrict__ inv_nf,
                            int* __restrict__ opi, int* __restrict__ opj) {
    int p = blockIdx.x * 256 + threadIdx.x;
    if (p >= PP) return;
    if (p >= P_) {          // padding: value collapses to eps
        inv_nr[p] = 0.f;
        inv_nf[p] = 0.f;
        opi[p] = 0;
        opj[p] = 0;
        return;
    }
    int i = (int)((1.0f + sqrtf(8.0f * (float)p + 1.0f)) * 0.5f);
    while (i * (i - 1) / 2 > p) --i;
    while ((i + 1) * i / 2 <= p) ++i;
    int j = p - i * (i - 1) / 2;

    const float* Gr = G;
    const float* Gf = G + NS * NS;
    float nr2 = Gr[i * NS + i] + Gr[j * NS + j] - 2.f * Gr[i * NS + j];
    float nf2 = Gf[i * NS + i] + Gf[j * NS + j] - 2.f * Gf[i * NS + j];
    inv_nr[p] = rsqrtf(fmaxf(nr2, 1e-30f));
    inv_nf[p] = rsqrtf(fmaxf(nf2, 1e-30f));
    opi[p] = i * DP_;       // row offsets in the PADDED bf16 matrices
    opj[p] = j * DP_;
}

// ============ K4: tile7 — 128p x 64q tiles on the PADDED 8192x8192 plane ============
// grid (64, 128), 256 thr. Rt bf16 [q][p] stride 136 (272 B rows, 16B-aligned).
// Thread = (pg = t&31 -> 4 p's) x (qg = t>>5 -> 8 q's).
__global__ void __launch_bounds__(256, 6)
tile7_kernel(const unsigned short* __restrict__ Sr16, const unsigned short* __restrict__ Sf16,
             const float* __restrict__ inv_nr, const float* __restrict__ inv_nf,
             const int* __restrict__ opi, const int* __restrict__ opj,
             float* __restrict__ partials) {
    __shared__ unsigned short Rt[64 * 136];
    __shared__ int   sIp[128], sJp[128];
    __shared__ float sInvF[128];
    __shared__ float wsum[4];

    int t  = threadIdx.x;
    int p0 = blockIdx.x * 128;
    int q0 = blockIdx.y * 64;

    if (t < 128) {
        int p = p0 + t;
        sIp[t]   = opi[p];
        sJp[t]   = opj[p];
        sInvF[t] = inv_nf[p];
    }

    // ---- stage Rt[q][p] = bf16(max((Sr[i_q][p]-Sr[j_q][p])*inv_nr[q], eps))
    #pragma unroll
    for (int s = 0; s < 4; ++s) {
        int task = t + 256 * s;             // 0..1023 = 64 q-rows x 16 slots of 8 p's
        int q = task >> 4, slot = task & 15;
        int gq = q0 + q;
        int oiq = opi[gq], ojq = opj[gq];
        float invr = inv_nr[gq];
        uint4 ua = *(const uint4*)(Sr16 + oiq + p0 + 8 * slot);
        uint4 ub = *(const uint4*)(Sr16 + ojq + p0 + 8 * slot);
        unsigned int r0 = f32_to_bf16_rne(fmaxf((bf16_lo(ua.x) - bf16_lo(ub.x)) * invr, EPSV));
        unsigned int r1 = f32_to_bf16_rne(fmaxf((bf16_hi(ua.x) - bf16_hi(ub.x)) * invr, EPSV));
        unsigned int r2 = f32_to_bf16_rne(fmaxf((bf16_lo(ua.y) - bf16_lo(ub.y)) * invr, EPSV));
        unsigned int r3 = f32_to_bf16_rne(fmaxf((bf16_hi(ua.y) - bf16_hi(ub.y)) * invr, EPSV));
        unsigned int r4 = f32_to_bf16_rne(fmaxf((bf16_lo(ua.z) - bf16_lo(ub.z)) * invr, EPSV));
        unsigned int r5 = f32_to_bf16_rne(fmaxf((bf16_hi(ua.z) - bf16_hi(ub.z)) * invr, EPSV));
        unsigned int r6 = f32_to_bf16_rne(fmaxf((bf16_lo(ua.w) - bf16_lo(ub.w)) * invr, EPSV));
        unsigned int r7 = f32_to_bf16_rne(fmaxf((bf16_hi(ua.w) - bf16_hi(ub.w)) * invr, EPSV));
        uint4 wv;
        wv.x = r0 | (r1 << 16);
        wv.y = r2 | (r3 << 16);
        wv.z = r4 | (r5 << 16);
        wv.w = r6 | (r7 << 16);
        *(uint4*)&Rt[q * 136 + 8 * slot] = wv;
    }
    __syncthreads();

    // ---- compute: 4 prows x 8 qcols per thread
    int pg = t & 31;          // prows 4pg..4pg+3
    int qg = t >> 5;          // qcols q0+8qg..+7
    float fr0[8], fr1[8], fr2[8], fr3[8];
    {
        #define LOAD_F(ARR, R)                                                         \
        {                                                                              \
            int prow = 4 * pg + (R);                                                   \
            int oi = sIp[prow], oj = sJp[prow];                                        \
            float invf = sInvF[prow];                                                  \
            uint4 ua = *(const uint4*)(Sf16 + oi + q0 + 8 * qg);                       \
            uint4 ub = *(const uint4*)(Sf16 + oj + q0 + 8 * qg);                       \
            ARR[0] = fmaxf((bf16_lo(ua.x) - bf16_lo(ub.x)) * invf, EPSV);              \
            ARR[1] = fmaxf((bf16_hi(ua.x) - bf16_hi(ub.x)) * invf, EPSV);              \
            ARR[2] = fmaxf((bf16_lo(ua.y) - bf16_lo(ub.y)) * invf, EPSV);              \
            ARR[3] = fmaxf((bf16_hi(ua.y) - bf16_hi(ub.y)) * invf, EPSV);              \
            ARR[4] = fmaxf((bf16_lo(ua.z) - bf16_lo(ub.z)) * invf, EPSV);              \
            ARR[5] = fmaxf((bf16_hi(ua.z) - bf16_hi(ub.z)) * invf, EPSV);              \
            ARR[6] = fmaxf((bf16_lo(ua.w) - bf16_lo(ub.w)) * invf, EPSV);              \
            ARR[7] = fmaxf((bf16_hi(ua.w) - bf16_hi(ub.w)) * invf, EPSV);              \
        }
        LOAD_F(fr0, 0)
        LOAD_F(fr1, 1)
        LOAD_F(fr2, 2)
        LOAD_F(fr3, 3)
        #undef LOAD_F
    }
    float acc = 0.f;
    #pragma unroll
    for (int k = 0; k < 8; ++k) {
        uint2 rt = *(const uint2*)&Rt[(8 * qg + k) * 136 + 4 * pg];  // prows 4pg..+3
        acc += fr0[k] * bf16_lo(rt.x) + fr1[k] * bf16_hi(rt.x)
             + fr2[k] * bf16_lo(rt.y) + fr3[k] * bf16_hi(rt.y);
    }

    #pragma unroll
    for (int off = 32; off > 0; off >>= 1) acc += __shfl_down(acc, off, 64);
    if ((t & 63) == 0) wsum[t >> 6] = acc;
    __syncthreads();
    if (t == 0) partials[blockIdx.y * 64 + blockIdx.x] = wsum[0] + wsum[1] + wsum[2] + wsum[3];
}

// ============ fallback norms + fp32 tile (proven round-1/3 path, D_ strides) ============
__global__ void norms_kernel(const float* __restrict__ Sr, const float* __restrict__ Sf,
                             float* __restrict__ inv_nr, float* __restrict__ inv_nf,
                             int* __restrict__ opi, int* __restrict__ opj) {
    int p = blockIdx.x;
    int i = (int)((1.0f + sqrtf(8.0f * (float)p + 1.0f)) * 0.5f);
    while (i * (i - 1) / 2 > p) --i;
    while ((i + 1) * i / 2 <= p) ++i;
    int j = p - i * (i - 1) / 2;

    const float4* ri = (const float4*)(Sr + (size_t)i * D_);
    const float4* rj = (const float4*)(Sr + (size_t)j * D_);
    const float4* fi = (const float4*)(Sf + (size_t)i * D_);
    const float4* fj = (const float4*)(Sf + (size_t)j * D_);

    float sr = 0.f, sf = 0.f;
    for (int d = threadIdx.x; d < D_ / 4; d += 256) {
        float4 a = ri[d], b = rj[d];
        float dx = a.x - b.x, dy = a.y - b.y, dz = a.z - b.z, dw = a.w - b.w;
        sr += dx * dx + dy * dy + dz * dz + dw * dw;
        float4 c2 = fi[d], e = fj[d];
        dx = c2.x - e.x; dy = c2.y - e.y; dz = c2.z - e.z; dw = c2.w - e.w;
        sf += dx * dx + dy * dy + dz * dz + dw * dw;
    }
    #pragma unroll
    for (int off = 32; off > 0; off >>= 1) {
        sr += __shfl_down(sr, off, 64);
        sf += __shfl_down(sf, off, 64);
    }
    __shared__ float wr[4], wf[4];
    int wave = threadIdx.x >> 6;
    if ((threadIdx.x & 63) == 0) { wr[wave] = sr; wf[wave] = sf; }
    __syncthreads();
    if (threadIdx.x == 0) {
        inv_nr[p] = 1.0f / sqrtf(wr[0] + wr[1] + wr[2] + wr[3]);
        inv_nf[p] = 1.0f / sqrtf(wf[0] + wf[1] + wf[2] + wf[3]);
        opi[p] = i * D_;
        opj[p] = j * D_;
    }
}

__global__ void __launch_bounds__(256, 6)
tile3_kernel(const float* __restrict__ Sr, const float* __restrict__ Sf,
             const float* __restrict__ inv_nr, const float* __restrict__ inv_nf,
             const int* __restrict__ opi, const int* __restrict__ opj,
             float* __restrict__ partials) {
    __shared__ float Rt[64][65];
    __shared__ int   sIp[64], sJp[64];
    __shared__ float sInvF[64];
    __shared__ float wsum[4];

    int t  = threadIdx.x;
    int p0 = blockIdx.x * 64, q0 = blockIdx.y * 64;

    if (t < 64) {
        int p = p0 + t;
        sIp[t]   = opi[p];
        sJp[t]   = opj[p];
        sInvF[t] = inv_nf[p];
    }
    {
        int c  = t & 15;
        int qr = t >> 4;
        #pragma unroll
        for (int pass = 0; pass < 4; ++pass) {
            int qq = qr + 16 * pass;
            int q  = q0 + qq;
            int oi = opi[q], oj = opj[q];
            float invr = inv_nr[q];
            const float4 a = *(const float4*)(Sr + oi + p0 + 4 * c);
            const float4 b = *(const float4*)(Sr + oj + p0 + 4 * c);
            Rt[4 * c + 0][qq] = fmaxf((a.x - b.x) * invr, EPSV);
            Rt[4 * c + 1][qq] = fmaxf((a.y - b.y) * invr, EPSV);
            Rt[4 * c + 2][qq] = fmaxf((a.z - b.z) * invr, EPSV);
            Rt[4 * c + 3][qq] = fmaxf((a.w - b.w) * invr, EPSV);
        }
    }
    __syncthreads();

    int qg = t & 15;
    int pg = t >> 4;
    float ax = 0.f, ay = 0.f, az = 0.f, aw = 0.f;
    #pragma unroll
    for (int pp = 0; pp < 4; ++pp) {
        int prow = pg + 16 * pp;
        int oi = sIp[prow], oj = sJp[prow];
        float invf = sInvF[prow];
        const float4 fa = *(const float4*)(Sf + oi + q0 + 4 * qg);
        const float4 fb = *(const float4*)(Sf + oj + q0 + 4 * qg);
        const float4 r  = *(const float4*)&Rt[prow][4 * qg];
        ax += fmaxf((fa.x - fb.x) * invf, EPSV) * r.x;
        ay += fmaxf((fa.y - fb.y) * invf, EPSV) * r.y;
        az += fmaxf((fa.z - fb.z) * invf, EPSV) * r.z;
        aw += fmaxf((fa.w - fb.w) * invf, EPSV) * r.w;
    }
    float acc = (ax + ay) + (az + aw);

    #pragma unroll
    for (int off = 32; off > 0; off >>= 1) acc += __shfl_down(acc, off, 64);
    int w = t >> 6;
    if ((t & 63) == 0) wsum[w] = acc;
    __syncthreads();
    if (t == 0) partials[blockIdx.y * NT + blockIdx.x] = wsum[0] + wsum[1] + wsum[2] + wsum[3];
}

// ============ K5: final deterministic reduce (1024 thr) ============
__global__ void reduce_kernel(const float* __restrict__ partials, int n, float* __restrict__ out) {
    float s = 0.f;
    for (int idx = threadIdx.x; idx < n; idx += 1024) s += partials[idx];
    #pragma unroll
    for (int off = 32; off > 0; off >>= 1) s += __shfl_down(s, off, 64);
    __shared__ float wbuf[16];
    int wave = threadIdx.x >> 6;
    if ((threadIdx.x & 63) == 0) wbuf[wave] = s;
    __syncthreads();
    if (threadIdx.x == 0) {
        float tot = 0.f;
        #pragma unroll
        for (int k = 0; k < 16; ++k) tot += wbuf[k];
        out[0] = tot;
    }
}

extern "C" void kernel_launch(void* const* d_in, const int* in_sizes, int n_in,
                              void* d_out, int out_size, void* d_ws, size_t ws_size,
                              hipStream_t stream) {
    const float* Sr = (const float*)d_in[0];
    const float* Sf = (const float*)d_in[1];
    float* out = (float*)d_out;

    // ws layout (all sub-buffer sizes are multiples of 16 B)
    char* w = (char*)d_ws;
    unsigned short* Sr16 = (unsigned short*)w;   w += (size_t)NS * DP_ * 2;             // 2.10 MB padded
    unsigned short* Sf16 = (unsigned short*)w;   w += (size_t)NS * DP_ * 2;             // 2.10 MB padded
    float* inv_nr = (float*)w;                   w += (size_t)PP * 4;
    float* inv_nf = (float*)w;                   w += (size_t)PP * 4;
    int*   opi    = (int*)w;                     w += (size_t)PP * 4;
    int*   opj    = (int*)w;                     w += (size_t)PP * 4;
    float* tpart  = (float*)w;                   w += (size_t)16384 * 4;                // max(8192, NT*NT)
    float* Gpart  = (float*)w;                   w += (size_t)KSPLIT * 2 * NS * NS * 4; // 8.4 MB
    float* G      = (float*)w;                   w += (size_t)2 * NS * NS * 4;          // 131 KB
    size_t need = (size_t)(w - (char*)d_ws);

    if (ws_size >= need) {
        pad_zero<<<8, 256, 0, stream>>>(Sr16, Sf16);
        dim3 gg(KSPLIT, 2);
        gram_cvt<<<gg, 256, 0, stream>>>(Sr, Sf, Sr16, Sf16, Gpart);
        gram_sum<<<128, 256, 0, stream>>>(Gpart, G);
        norm_finish<<<32, 256, 0, stream>>>(G, inv_nr, inv_nf, opi, opj);
        dim3 grid(64, 128);
        tile7_kernel<<<grid, 256, 0, stream>>>(Sr16, Sf16, inv_nr, inv_nf, opi, opj, tpart);
        reduce_kernel<<<1, 1024, 0, stream>>>(tpart, 8192, out);
    } else {
        norms_kernel<<<P_, 256, 0, stream>>>(Sr, Sf, inv_nr, inv_nf, opi, opj);
        dim3 grid(NT, NT);
        tile3_kernel<<<grid, 256, 0, stream>>>(Sr, Sf, inv_nr, inv_nf, opi, opj, tpart);
        reduce_kernel<<<1, 1024, 0, stream>>>(tpart, NT * NT, out);
    }
}